// Round 1
// baseline (340.232 us; speedup 1.0000x reference)
//
#include <hip/hip_runtime.h>
#include <hip/hip_fp16.h>
#include <stdint.h>

// Problem dims (fixed by setup_inputs): x[8,2048,2048] f32, w[2048,2048] f32,
// bias[2048] f32, scales scalar. M = 16384, N = 2048, K = 2048. Output f16
// values stored as f32 in d_out.
#define MDIM 16384
#define NDIM 2048
#define KDIM 2048

typedef __attribute__((ext_vector_type(4))) float f32x4;

// ---------------------------------------------------------------------------
// Bit-exact f32 -> e4m3fn (OCP) with RTNE, after clip to +-448.
// Matches: jnp.clip(x/s, -448, 448).astype(float8_e4m3fn)
// ---------------------------------------------------------------------------
__device__ __forceinline__ unsigned f32_to_e4m3(float x) {
    float q = fminf(448.f, fmaxf(-448.f, x));
    unsigned ub = __float_as_uint(q);
    unsigned sgn = (ub >> 24) & 0x80u;
    float aq = fabsf(q);
    int E = (int)((__float_as_uint(aq) >> 23) & 0xff) - 127;
    if (E < -6) E = -6;                       // denormal bucket
    // quantum = 2^(E-3), exact power of two
    float quantum = __uint_as_float((unsigned)(E + 124) << 23);
    int m = (int)rintf(aq / quantum);         // RTNE; exact division (pow2)
    if (m == 16) { m = 8; E += 1; }           // mantissa overflow -> next exp
    unsigned bits;
    if (m < 8) {
        bits = sgn | (unsigned)m;             // denormal (E == -6): val = m*2^-9
    } else {
        bits = sgn | ((unsigned)(E + 7) << 3) | (unsigned)(m - 8);
    }
    return bits;
}

// ---------------------------------------------------------------------------
// Quantize kernel: 16 f32 -> 16 fp8 bytes per thread-iteration.
// ---------------------------------------------------------------------------
__global__ void quant_fp8_kernel(const float* __restrict__ x,
                                 uint8_t* __restrict__ q,
                                 const float* __restrict__ scale,
                                 unsigned n16) {
    float sc = scale[0];
    unsigned i = blockIdx.x * blockDim.x + threadIdx.x;
    unsigned stride = gridDim.x * blockDim.x;
    for (; i < n16; i += stride) {
        const float4* xp = (const float4*)(x + (size_t)i * 16);
        uint32_t w[4];
#pragma unroll
        for (int j = 0; j < 4; ++j) {
            float4 v = xp[j];
            unsigned b0 = f32_to_e4m3(v.x / sc);
            unsigned b1 = f32_to_e4m3(v.y / sc);
            unsigned b2 = f32_to_e4m3(v.z / sc);
            unsigned b3 = f32_to_e4m3(v.w / sc);
            w[j] = b0 | (b1 << 8) | (b2 << 16) | (b3 << 24);
        }
        ((uint4*)q)[i] = make_uint4(w[0], w[1], w[2], w[3]);
    }
}

// ---------------------------------------------------------------------------
// GEMM: C[M][N] = Aq[M][K] * Bq[N][K]^T (both fp8 e4m3, K contiguous).
// 128x128 tile, BK=64, 4 waves (2x2 of 64x64), mfma_f32_16x16x32_fp8_fp8.
// Staging via global_load_lds width=16 (linear LDS, wave-contiguous).
// Epilogue: out = float( half(acc*s) + half(bias) ), stored as f32.
// ---------------------------------------------------------------------------
#define BM 128
#define BN 128
#define BK 64

__device__ __forceinline__ void gload_lds16(const uint8_t* g, uint8_t* l) {
    __builtin_amdgcn_global_load_lds(
        (const __attribute__((address_space(1))) void*)g,
        (__attribute__((address_space(3))) void*)l, 16, 0, 0);
}

__global__ __launch_bounds__(256) void gemm_fp8_kernel(
    const uint8_t* __restrict__ Aq, const uint8_t* __restrict__ Bq,
    const float* __restrict__ bias, const float* __restrict__ s_in,
    const float* __restrict__ s_w, float* __restrict__ out) {

    __shared__ uint8_t lsA[BM * BK];
    __shared__ uint8_t lsB[BN * BK];

    // XCD-aware bijective swizzle (nwg = 2048, divisible by 8)
    int nwg = gridDim.x;
    int cpx = nwg >> 3;
    int bid = blockIdx.x;
    int swz = (bid & 7) * cpx + (bid >> 3);
    int tiles_n = NDIM / BN;                 // 16
    int tm = swz / tiles_n;
    int tn = swz % tiles_n;
    int row0 = tm * BM;
    int col0 = tn * BN;

    int t = threadIdx.x;
    int lane = t & 63;
    int wid = t >> 6;
    int wr = wid >> 1;                       // wave row 0..1
    int wc = wid & 1;                        // wave col 0..1

    f32x4 acc[4][4];
#pragma unroll
    for (int m = 0; m < 4; ++m)
#pragma unroll
        for (int n = 0; n < 4; ++n)
            acc[m][n] = (f32x4){0.f, 0.f, 0.f, 0.f};

    int r15 = lane & 15;
    int kgrp = (lane >> 4) * 8;

    for (int kt = 0; kt < KDIM / BK; ++kt) {
        // ---- stage A,B tiles (each 8 KiB = 512 x 16B chunks, 256 threads) ----
#pragma unroll
        for (int i = 0; i < 2; ++i) {
            int c = i * 256 + t;             // chunk id: row = c>>2, 16B col = c&3
            gload_lds16(Aq + (size_t)(row0 + (c >> 2)) * KDIM + kt * BK + (c & 3) * 16,
                        &lsA[c * 16]);
        }
#pragma unroll
        for (int i = 0; i < 2; ++i) {
            int c = i * 256 + t;
            gload_lds16(Bq + (size_t)(col0 + (c >> 2)) * KDIM + kt * BK + (c & 3) * 16,
                        &lsB[c * 16]);
        }
        __syncthreads();

#pragma unroll
        for (int ks = 0; ks < 2; ++ks) {
            int kb = ks * 32 + kgrp;
            long af[4], bf[4];
#pragma unroll
            for (int m = 0; m < 4; ++m)
                af[m] = *(const long*)&lsA[(wr * 64 + m * 16 + r15) * BK + kb];
#pragma unroll
            for (int n = 0; n < 4; ++n)
                bf[n] = *(const long*)&lsB[(wc * 64 + n * 16 + r15) * BK + kb];
#pragma unroll
            for (int m = 0; m < 4; ++m)
#pragma unroll
                for (int n = 0; n < 4; ++n)
                    acc[m][n] = __builtin_amdgcn_mfma_f32_16x16x32_fp8_fp8(
                        af[m], bf[n], acc[m][n], 0, 0, 0);
        }
        __syncthreads();
    }

    // ---- epilogue: fp16 double-rounding emulation, store f32 ----
    float s = s_in[0] * s_w[0];
    int crow = row0 + wr * 64;
    int ccol = col0 + wc * 64;
#pragma unroll
    for (int n = 0; n < 4; ++n) {
        int col = ccol + n * 16 + r15;
        __half hb = __float2half(bias[col]);
#pragma unroll
        for (int m = 0; m < 4; ++m) {
            int rbase = crow + m * 16 + (lane >> 4) * 4;
#pragma unroll
            for (int r = 0; r < 4; ++r) {
                __half h = __float2half(acc[m][n][r] * s);
                out[(size_t)(rbase + r) * NDIM + col] = __half2float(__hadd(h, hb));
            }
        }
    }
}

// ---------------------------------------------------------------------------
extern "C" void kernel_launch(void* const* d_in, const int* in_sizes, int n_in,
                              void* d_out, int out_size, void* d_ws, size_t ws_size,
                              hipStream_t stream) {
    const float* x      = (const float*)d_in[0];   // [16384, 2048]
    const float* weight = (const float*)d_in[1];   // [2048, 2048]
    const float* bias   = (const float*)d_in[2];   // [2048]
    const float* s_in   = (const float*)d_in[3];   // [1]
    const float* s_w    = (const float*)d_in[4];   // [1]
    float* out          = (float*)d_out;           // [16384, 2048] (f16 values as f32)

    uint8_t* xq = (uint8_t*)d_ws;                                  // 33.5 MB
    uint8_t* wq = (uint8_t*)d_ws + (size_t)MDIM * KDIM;            // 4.2 MB

    // quantize x: 16384*2048/16 = 2,097,152 chunks
    quant_fp8_kernel<<<2048, 256, 0, stream>>>(x, xq, s_in, (unsigned)(MDIM * (size_t)KDIM / 16));
    // quantize w: 2048*2048/16 = 262,144 chunks
    quant_fp8_kernel<<<512, 256, 0, stream>>>(weight, wq, s_w, (unsigned)(NDIM * (size_t)KDIM / 16));

    dim3 grid((MDIM / BM) * (NDIM / BN));   // 128 * 16 = 2048
    gemm_fp8_kernel<<<grid, 256, 0, stream>>>(xq, wq, bias, s_in, s_w, out);
}

// Round 2
// 221.226 us; speedup vs baseline: 1.5379x; 1.5379x over previous
//
#include <hip/hip_runtime.h>
#include <hip/hip_fp16.h>
#include <stdint.h>

// Problem dims (fixed by setup_inputs): x[8,2048,2048] f32, w[2048,2048] f32,
// bias[2048] f32, scales scalar. M = 16384, N = 2048, K = 2048. Output f16
// values stored as f32 in d_out.
#define MDIM 16384
#define NDIM 2048
#define KDIM 2048

typedef __attribute__((ext_vector_type(4))) float f32x4;

// ---------------------------------------------------------------------------
// Bit-exact f32 -> e4m3fn (OCP) with RTNE, after clip to +-448.
// Matches: jnp.clip(x/s, -448, 448).astype(float8_e4m3fn)
// ---------------------------------------------------------------------------
__device__ __forceinline__ unsigned f32_to_e4m3(float x) {
    float q = fminf(448.f, fmaxf(-448.f, x));
    unsigned ub = __float_as_uint(q);
    unsigned sgn = (ub >> 24) & 0x80u;
    float aq = fabsf(q);
    int E = (int)((__float_as_uint(aq) >> 23) & 0xff) - 127;
    if (E < -6) E = -6;                       // denormal bucket
    // quantum = 2^(E-3), exact power of two
    float quantum = __uint_as_float((unsigned)(E + 124) << 23);
    int m = (int)rintf(aq / quantum);         // RTNE; exact division (pow2)
    if (m == 16) { m = 8; E += 1; }           // mantissa overflow -> next exp
    unsigned bits;
    if (m < 8) {
        bits = sgn | (unsigned)m;             // denormal (E == -6): val = m*2^-9
    } else {
        bits = sgn | ((unsigned)(E + 7) << 3) | (unsigned)(m - 8);
    }
    return bits;
}

// ---------------------------------------------------------------------------
// Quantize kernel: 16 f32 -> 16 fp8 bytes per thread-iteration.
// ---------------------------------------------------------------------------
__global__ void quant_fp8_kernel(const float* __restrict__ x,
                                 uint8_t* __restrict__ q,
                                 const float* __restrict__ scale,
                                 unsigned n16) {
    float sc = scale[0];
    unsigned i = blockIdx.x * blockDim.x + threadIdx.x;
    unsigned stride = gridDim.x * blockDim.x;
    for (; i < n16; i += stride) {
        const float4* xp = (const float4*)(x + (size_t)i * 16);
        uint32_t w[4];
#pragma unroll
        for (int j = 0; j < 4; ++j) {
            float4 v = xp[j];
            unsigned b0 = f32_to_e4m3(v.x / sc);
            unsigned b1 = f32_to_e4m3(v.y / sc);
            unsigned b2 = f32_to_e4m3(v.z / sc);
            unsigned b3 = f32_to_e4m3(v.w / sc);
            w[j] = b0 | (b1 << 8) | (b2 << 16) | (b3 << 24);
        }
        ((uint4*)q)[i] = make_uint4(w[0], w[1], w[2], w[3]);
    }
}

// ---------------------------------------------------------------------------
// GEMM: C[M][N] = Aq[M][K] * Bq[N][K]^T (both fp8 e4m3, K contiguous).
// 128x128 tile, BK=64, 4 waves (2x2 of 64x64), mfma_f32_16x16x32_fp8_fp8.
//
// LDS bank-conflict fix (rule #21 compliant): LDS holds 16B chunks under the
// bijection  P(row,c) = row*4 + ((c+row)&3)   (c = 16B chunk within the 64B
// row).  global_load_lds dest stays linear; the *global source* is permuted
// with the inverse (row = p>>2, c = ((p&3)-row)&3); fragment reads apply the
// same permutation.  Read-side 8B-slot index = 8(row&1) + 2((c+row)&3) + half
// covers each of the 16 bank-slots exactly 4x per wave read (minimum for a
// 512B wave64 ds_read_b64) vs the previous 8-way conflict.
// ---------------------------------------------------------------------------
#define BM 128
#define BN 128
#define BK 64

__device__ __forceinline__ void gload_lds16(const uint8_t* g, uint8_t* l) {
    __builtin_amdgcn_global_load_lds(
        (const __attribute__((address_space(1))) void*)g,
        (__attribute__((address_space(3))) void*)l, 16, 0, 0);
}

__global__ __launch_bounds__(256) void gemm_fp8_kernel(
    const uint8_t* __restrict__ Aq, const uint8_t* __restrict__ Bq,
    const float* __restrict__ bias, const float* __restrict__ s_in,
    const float* __restrict__ s_w, float* __restrict__ out) {

    __shared__ uint8_t lsA[BM * BK];
    __shared__ uint8_t lsB[BN * BK];

    // XCD-aware bijective swizzle (nwg = 2048, divisible by 8)
    int nwg = gridDim.x;
    int cpx = nwg >> 3;
    int bid = blockIdx.x;
    int swz = (bid & 7) * cpx + (bid >> 3);
    int tiles_n = NDIM / BN;                 // 16
    int tm = swz / tiles_n;
    int tn = swz % tiles_n;
    int row0 = tm * BM;
    int col0 = tn * BN;

    int t = threadIdx.x;
    int lane = t & 63;
    int wid = t >> 6;
    int wr = wid >> 1;                       // wave row 0..1
    int wc = wid & 1;                        // wave col 0..1

    f32x4 acc[4][4];
#pragma unroll
    for (int m = 0; m < 4; ++m)
#pragma unroll
        for (int n = 0; n < 4; ++n)
            acc[m][n] = (f32x4){0.f, 0.f, 0.f, 0.f};

    int r15 = lane & 15;
    int g   = lane >> 4;                     // 0..3
    int gh  = g >> 1;                        // chunk-within-32K select
    int h8  = (g & 1) << 3;                  // 8B half within chunk

    // Staging source coordinates for the 2 chunks this thread loads per tile:
    // p = i*256 + t ; row = p>>2 ; c = ((p&3) - row) & 3
    int p0 = t, p1 = 256 + t;
    int srow0 = p0 >> 2, sc0 = ((p0 & 3) - srow0) & 3;
    int srow1 = p1 >> 2, sc1 = ((p1 & 3) - srow1) & 3;

    const uint8_t* Abase = Aq + (size_t)row0 * KDIM;
    const uint8_t* Bbase = Bq + (size_t)col0 * KDIM;

    for (int kt = 0; kt < KDIM / BK; ++kt) {
        int koff = kt * BK;
        // ---- stage A,B tiles (each 8 KiB = 512 x 16B chunks, 256 threads) ----
        gload_lds16(Abase + (size_t)srow0 * KDIM + koff + sc0 * 16, &lsA[p0 * 16]);
        gload_lds16(Abase + (size_t)srow1 * KDIM + koff + sc1 * 16, &lsA[p1 * 16]);
        gload_lds16(Bbase + (size_t)srow0 * KDIM + koff + sc0 * 16, &lsB[p0 * 16]);
        gload_lds16(Bbase + (size_t)srow1 * KDIM + koff + sc1 * 16, &lsB[p1 * 16]);
        __syncthreads();

#pragma unroll
        for (int ks = 0; ks < 2; ++ks) {
            int cbase = 2 * ks + gh;         // logical 16B chunk within row
            long af[4], bf[4];
#pragma unroll
            for (int m = 0; m < 4; ++m) {
                int rowA = wr * 64 + m * 16 + r15;
                int perm = (cbase + rowA) & 3;
                af[m] = *(const long*)&lsA[rowA * BK + (perm << 4) + h8];
            }
#pragma unroll
            for (int n = 0; n < 4; ++n) {
                int rowB = wc * 64 + n * 16 + r15;
                int perm = (cbase + rowB) & 3;
                bf[n] = *(const long*)&lsB[rowB * BK + (perm << 4) + h8];
            }
#pragma unroll
            for (int m = 0; m < 4; ++m)
#pragma unroll
                for (int n = 0; n < 4; ++n)
                    acc[m][n] = __builtin_amdgcn_mfma_f32_16x16x32_fp8_fp8(
                        af[m], bf[n], acc[m][n], 0, 0, 0);
        }
        __syncthreads();
    }

    // ---- epilogue: fp16 double-rounding emulation, store f32 ----
    float s = s_in[0] * s_w[0];
    int crow = row0 + wr * 64;
    int ccol = col0 + wc * 64;
#pragma unroll
    for (int n = 0; n < 4; ++n) {
        int col = ccol + n * 16 + r15;
        __half hb = __float2half(bias[col]);
#pragma unroll
        for (int m = 0; m < 4; ++m) {
            int rbase = crow + m * 16 + g * 4;
#pragma unroll
            for (int r = 0; r < 4; ++r) {
                __half h = __float2half(acc[m][n][r] * s);
                out[(size_t)(rbase + r) * NDIM + col] = __half2float(__hadd(h, hb));
            }
        }
    }
}

// ---------------------------------------------------------------------------
extern "C" void kernel_launch(void* const* d_in, const int* in_sizes, int n_in,
                              void* d_out, int out_size, void* d_ws, size_t ws_size,
                              hipStream_t stream) {
    const float* x      = (const float*)d_in[0];   // [16384, 2048]
    const float* weight = (const float*)d_in[1];   // [2048, 2048]
    const float* bias   = (const float*)d_in[2];   // [2048]
    const float* s_in   = (const float*)d_in[3];   // [1]
    const float* s_w    = (const float*)d_in[4];   // [1]
    float* out          = (float*)d_out;           // [16384, 2048] (f16 values as f32)

    uint8_t* xq = (uint8_t*)d_ws;                                  // 33.5 MB
    uint8_t* wq = (uint8_t*)d_ws + (size_t)MDIM * KDIM;            // 4.2 MB

    // quantize x: 16384*2048/16 = 2,097,152 chunks
    quant_fp8_kernel<<<2048, 256, 0, stream>>>(x, xq, s_in, (unsigned)(MDIM * (size_t)KDIM / 16));
    // quantize w: 2048*2048/16 = 262,144 chunks
    quant_fp8_kernel<<<512, 256, 0, stream>>>(weight, wq, s_w, (unsigned)(NDIM * (size_t)KDIM / 16));

    dim3 grid((MDIM / BM) * (NDIM / BN));   // 128 * 16 = 2048
    gemm_fp8_kernel<<<grid, 256, 0, stream>>>(xq, wq, bias, s_in, s_w, out);
}